// Round 10
// baseline (233.022 us; speedup 1.0000x reference)
//
#include <hip/hip_runtime.h>
#include <math.h>

#define HH 512
#define WW 512
#define NCH 48
#define HWPIX (HH * WW)

#define TW 16            // tile width (pixels)
#define TH 8             // tile height
#define HW_HALO 18       // TW + 2
#define HH_HALO 10       // TH + 2
#define NHALO (HW_HALO * HH_HALO)   // 180 halo pixels
#define ASTRIDE 12       // floats per pixel in packed A (9 + 3 pad, 16B-aligned)

// DMA-native LDS layout (R5-proven correct): slot(p, ch) =
//   (p>>6)*780 + ch*65 + (p&63)      [65 = 64 lanes + 1 pad, 780 = 12*65]
// Pad keeps the quad read pattern conflict-free; dest of global_load_lds is
// wave-uniform base + lane*16B, matching (p&63) as the lane offset.
#define BLK_STRIDE 65
#define WAVE_STRIDE 780  // 12 * BLK_STRIDE
#define BUF_SLOTS (36 * BLK_STRIDE)   // 3 waves x 12 chunks

#define NBLOCKS 1024     // 2048 tiles / 2 tiles per block

// ---------------------------------------------------------------------------
// global -> LDS direct DMA (dest = wave-uniform base + lane*16B)
// ---------------------------------------------------------------------------
__device__ __forceinline__ void gl2lds16(const float4* g, float4* l) {
  __builtin_amdgcn_global_load_lds(
      (const __attribute__((address_space(1))) void*)g,
      (__attribute__((address_space(3))) void*)l, 16, 0, 0);
}

// ---------------------------------------------------------------------------
// Kernel 1: packed stencil weights A (border masks + 1/dg + MSQ folded in).
// Pixel-major: A[pix*12 + k] multiplies x[h-1+k/3, w-1+k%3].
// ---------------------------------------------------------------------------
__global__ __launch_bounds__(256) void compute_A_kernel(
    const float* __restrict__ Dt, const float* __restrict__ dg,
    float* __restrict__ A) {
  int pix = blockIdx.x * blockDim.x + threadIdx.x;
  int h = pix >> 9;
  int w = pix & (WW - 1);
  int hm = (h == 0) ? HH - 1 : h - 1;
  int hp = (h == HH - 1) ? 0 : h + 1;
  int wm = (w == 0) ? WW - 1 : w - 1;
  int wp = (w == WW - 1) ? 0 : w + 1;

  float aC, cC, bC, cL, bL, cR, bR, aU, bU, aD, bD;
  float bUL, bUR, bDL, bDR;
  {
    int p;
    p = (h * WW + w) * 3;   aC = Dt[p]; cC = Dt[p + 1]; bC = Dt[p + 2];
    p = (h * WW + wm) * 3;  cL = Dt[p + 1]; bL = Dt[p + 2];
    p = (h * WW + wp) * 3;  cR = Dt[p + 1]; bR = Dt[p + 2];
    p = (hm * WW + w) * 3;  aU = Dt[p]; bU = Dt[p + 2];
    p = (hp * WW + w) * 3;  aD = Dt[p]; bD = Dt[p + 2];
    p = (hm * WW + wm) * 3; bUL = Dt[p + 2];
    p = (hm * WW + wp) * 3; bUR = Dt[p + 2];
    p = (hp * WW + wm) * 3; bDL = Dt[p + 2];
    p = (hp * WW + wp) * 3; bDR = Dt[p + 2];
  }

  float A0 = (fabsf(bDL) - bDL + fabsf(bC) - bC) * 0.25f;
  float A1 = (cL + cC - fabsf(bL) - fabsf(bC)) * 0.5f;
  float A2 = (fabsf(bUL) + bUL + fabsf(bC) + bC) * 0.25f;
  float A3 = (aD + aC - fabsf(bD) - fabsf(bC)) * 0.5f;
  float A4 = -(aD + 2.f * aC + aU) * 0.5f
             - (fabsf(bDL) - bDL + fabsf(bUL) + bUL) * 0.25f
             - (fabsf(bDR) + bDR + fabsf(bUR) - bUR) * 0.25f
             + (fabsf(bD) + fabsf(bU) + fabsf(bR) + fabsf(bL) + 2.f * fabsf(bC)) * 0.5f
             - (cR + 2.f * cC + cL) * 0.5f;
  float A5 = (aU + aC - fabsf(bU) - fabsf(bC)) * 0.5f;
  float A6 = (fabsf(bDR) + bDR + fabsf(bC) + bC) * 0.25f;
  float A7 = (cR + cC - fabsf(bR) - fabsf(bC)) * 0.5f;
  float A8 = (fabsf(bUR) - bUR + fabsf(bC) - bC) * 0.25f;

  bool ru = (h > 0), rd = (h < HH - 1), cl = (w > 0), cr = (w < WW - 1);
  if (!(ru && cl)) A0 = 0.f;
  if (!ru)         A1 = 0.f;
  if (!(ru && cr)) A2 = 0.f;
  if (!cl)         A3 = 0.f;
  if (!cr)         A5 = 0.f;
  if (!(rd && cl)) A6 = 0.f;
  if (!rd)         A7 = 0.f;
  if (!(rd && cr)) A8 = 0.f;

  float g = 1.0f / dg[pix];
  float4* Ao = (float4*)A + (size_t)pix * 3;
  Ao[0] = make_float4(A0 * g, A1 * g, A2 * g, A3 * g);
  Ao[1] = make_float4(A4 * g + 0.1f, A5 * g, A6 * g, A7 * g);
  Ao[2] = make_float4(A8 * g, 0.f, 0.f, 0.f);
}

// ---------------------------------------------------------------------------
// Phase-2 (pixel-pair compute) on a 65-stride LDS buffer.  R5-proven body.
// ---------------------------------------------------------------------------
__device__ __forceinline__ void phase2(
    const float4* __restrict__ buf, const float* __restrict__ lse_s,
    float* __restrict__ xn, int th0, int tw0,
    int sub, int pr, int pc0,
    const float* wt0, const float* wt1,
    float ha0, float hc0, float hb0,
    float ha1, float hc1, float hb1) {
  int pix0 = (th0 + pr) * WW + (tw0 + pc0);

  // lse taps (halo coords: center of px0 = (pr+1, pc0+1))
  int lc0 = (pr + 1) * HW_HALO + (pc0 + 1);
  float l0C = lse_s[lc0];
  float l0R = lse_s[lc0 + 1];                 // = l1C
  float l1R = lse_s[lc0 + 2];
  float l0D = lse_s[lc0 + HW_HALO];
  float l1D = lse_s[lc0 + HW_HALO + 1];
  float dld0 = l0C - l0D, dlr0 = l0C - l0R;
  float dld1 = l0R - l1D, dlr1 = l0R - l1R;

  // LDS base offsets of the 3x4 patch (ch*65 added per read)
  int base4[3][4];
#pragma unroll
  for (int dr = 0; dr < 3; dr++)
#pragma unroll
    for (int dc = 0; dc < 4; dc++) {
      int p = (pr + dr) * HW_HALO + pc0 + dc;
      base4[dr][dc] = (p >> 6) * WAVE_STRIDE + (p & 63);
    }

  float4 vals0[3], vals1[3];
  float sum0 = 0.f, sum1 = 0.f;
#pragma unroll
  for (int j = 0; j < 3; j++) {
    int ch = j * 4 + sub;
    int choff = ch * BLK_STRIDE;
    float4 q[3][4];
#pragma unroll
    for (int dr = 0; dr < 3; dr++)
#pragma unroll
      for (int dc = 0; dc < 4; dc++) q[dr][dc] = buf[base4[dr][dc] + choff];

    float4 val0, val1;
#define COMP(f)                                                                \
    {                                                                          \
      float s0_ = wt0[0] * q[0][0].f + wt0[1] * q[0][1].f + wt0[2] * q[0][2].f \
                + wt0[3] * q[1][0].f + wt0[4] * q[1][1].f + wt0[5] * q[1][2].f \
                + wt0[6] * q[2][0].f + wt0[7] * q[2][1].f + wt0[8] * q[2][2].f;\
      float v00 = q[2][1].f - q[1][1].f + dld0;                                \
      float v10 = q[1][2].f - q[1][1].f + dlr0;                                \
      float vv0 = s0_ + 0.5f * (ha0 * v00 * v00 + hc0 * v10 * v10) +           \
                  hb0 * (v00 * v10);                                           \
      val0.f = vv0; sum0 += vv0;                                               \
      float s1_ = wt1[0] * q[0][1].f + wt1[1] * q[0][2].f + wt1[2] * q[0][3].f \
                + wt1[3] * q[1][1].f + wt1[4] * q[1][2].f + wt1[5] * q[1][3].f \
                + wt1[6] * q[2][1].f + wt1[7] * q[2][2].f + wt1[8] * q[2][3].f;\
      float v01 = q[2][2].f - q[1][2].f + dld1;                                \
      float v11 = q[1][3].f - q[1][2].f + dlr1;                                \
      float vv1 = s1_ + 0.5f * (ha1 * v01 * v01 + hc1 * v11 * v11) +           \
                  hb1 * (v01 * v11);                                           \
      val1.f = vv1; sum1 += vv1;                                               \
    }
    COMP(x) COMP(y) COMP(z) COMP(w)
#undef COMP
    vals0[j] = val0;
    vals1[j] = val1;
  }

  // channel mean across the 4-thread quad (48 channels per pixel)
  sum0 += __shfl_xor(sum0, 1); sum0 += __shfl_xor(sum0, 2);
  sum1 += __shfl_xor(sum1, 1); sum1 += __shfl_xor(sum1, 2);
  float mean0 = sum0 * (1.0f / 48.0f);
  float mean1 = sum1 * (1.0f / 48.0f);

  // centers re-read from LDS
  int cb0 = (lc0 >> 6) * WAVE_STRIDE + (lc0 & 63);
  int lc1 = lc0 + 1;
  int cb1 = (lc1 >> 6) * WAVE_STRIDE + (lc1 & 63);
  float4* op0 = (float4*)(xn + (size_t)pix0 * NCH);
  float4* op1 = op0 + 12;
#pragma unroll
  for (int j = 0; j < 3; j++) {
    int ch = j * 4 + sub;
    int choff = ch * BLK_STRIDE;
    float4 c0 = buf[cb0 + choff];
    float4 c1 = buf[cb1 + choff];
    float4 r0, r1;
    r0.x = c0.x + 0.2f * fminf(fmaxf(vals0[j].x - mean0, -1e8f), 1e8f);
    r0.y = c0.y + 0.2f * fminf(fmaxf(vals0[j].y - mean0, -1e8f), 1e8f);
    r0.z = c0.z + 0.2f * fminf(fmaxf(vals0[j].z - mean0, -1e8f), 1e8f);
    r0.w = c0.w + 0.2f * fminf(fmaxf(vals0[j].w - mean0, -1e8f), 1e8f);
    r1.x = c1.x + 0.2f * fminf(fmaxf(vals1[j].x - mean1, -1e8f), 1e8f);
    r1.y = c1.y + 0.2f * fminf(fmaxf(vals1[j].y - mean1, -1e8f), 1e8f);
    r1.z = c1.z + 0.2f * fminf(fmaxf(vals1[j].z - mean1, -1e8f), 1e8f);
    r1.w = c1.w + 0.2f * fminf(fmaxf(vals1[j].w - mean1, -1e8f), 1e8f);
    op0[ch] = r0;
    op1[ch] = r1;
  }
}

// ---------------------------------------------------------------------------
// Fused Euler step, 2-tile intra-block pipeline (R10).
// Block b handles tiles tid0 and tid0+128 (same XCD band, rows 32 apart):
//   stage A (reg + in-register lse: R6-proven, hides latency at kernel start)
//   bar1
//   issue DMA for tile B (global_load_lds, no VGPR round-trip)
//   prefetch tile-A weights were pre-bar1; phase-2 A runs ~2000+ cy
//     -> tile-B DMA latency fully hidden under it (fixes R5's failure mode)
//   bar2 (drains vmcnt -> B visible)
//   load tile-B weights (hidden under B's lse exp chain from LDS)
//   bar3; phase-2 B.
// Occupancy: LDS 76.4 KB -> 2 blocks/CU (8 waves).  The bet (R9 post-mortem):
// intra-block latency hiding beats the cross-block TLP we give up.
// ---------------------------------------------------------------------------
__global__ __launch_bounds__(256, 2) void step_fused_kernel(
    const float* __restrict__ x, const float* __restrict__ A,
    const float* __restrict__ hinv, float* __restrict__ xn) {
  __shared__ float4 bufA[BUF_SLOTS];         // 37,440 B
  __shared__ float4 bufB[BUF_SLOTS];         // 37,440 B
  __shared__ float lseA[192];                // 768 B (180 used)
  __shared__ float lseB[192];                // 768 B

  int b = blockIdx.x;                        // 0..1023
  int tid0 = (b & 7) * 256 + (b >> 3);       // XCD-band swizzle
  int th0A = (tid0 >> 5) * TH;
  int tw0A = (tid0 & 31) * TW;
  int th0B = th0A + 32;                      // tid0+128 = +4 tile rows
  int tw0B = tw0A;

  int t = threadIdx.x;
  int sub = t & 3;
  int pair = t >> 2;
  int pr = pair >> 3;
  int pc0 = (pair & 7) * 2;

  bool stager = (t < NHALO);
  int wv = t >> 6;                           // wave id (uniform in wave)
  int r = t / HW_HALO;
  int c = t - r * HW_HALO;
  int lane = t & 63;

  // ---- Stage A: reg loads + in-register lse + ds_write (65-layout) ------
  if (stager) {
    int gh = (th0A + r - 1) & (HH - 1);
    int gw = (tw0A + c - 1) & (WW - 1);
    const float4* src = (const float4*)x + (size_t)(gh * WW + gw) * 12;
    float4 v[12];
#pragma unroll
    for (int i = 0; i < 12; i++) v[i] = src[i];
    float4 mv = v[0];
#pragma unroll
    for (int i = 1; i < 12; i++) {
      mv.x = fmaxf(mv.x, v[i].x); mv.y = fmaxf(mv.y, v[i].y);
      mv.z = fmaxf(mv.z, v[i].z); mv.w = fmaxf(mv.w, v[i].w);
    }
    float m = fmaxf(fmaxf(mv.x, mv.y), fmaxf(mv.z, mv.w));
    float sx = 0.f, sy = 0.f, sz = 0.f, sw = 0.f;
    float4* dst = bufA + wv * WAVE_STRIDE + lane;
#pragma unroll
    for (int i = 0; i < 12; i++) {
      sx += __expf(v[i].x - m); sy += __expf(v[i].y - m);
      sz += __expf(v[i].z - m); sw += __expf(v[i].w - m);
      dst[i * BLK_STRIDE] = v[i];
    }
    lseA[t] = m + __logf((sx + sy) + (sz + sw));
  }

  // ---- Prefetch tile-A weights + hinv (pre-barrier) ---------------------
  int pixA0 = (th0A + pr) * WW + (tw0A + pc0);
  const float4* apA0 = (const float4*)A + (size_t)pixA0 * 3;
  const float4* apA1 = apA0 + 3;
  float4 aA0 = apA0[0], aA1 = apA0[1], aA2 = apA0[2];
  float4 bA0 = apA1[0], bA1 = apA1[1], bA2 = apA1[2];
  const float2* hpA = (const float2*)(hinv + (size_t)pixA0 * 3);
  float2 hA01 = hpA[0], hA23 = hpA[1], hA45 = hpA[2];

  __syncthreads();   // bar1: A staged

  // ---- Issue DMA for tile B (fire-and-forget; hides under phase-2 A) ----
  if (stager) {
    int gh = (th0B + r - 1) & (HH - 1);
    int gw = (tw0B + c - 1) & (WW - 1);
    const float4* src = (const float4*)x + (size_t)(gh * WW + gw) * 12;
    float4* dst = bufB + wv * WAVE_STRIDE;   // wave-uniform base
#pragma unroll
    for (int i = 0; i < 12; i++)
      gl2lds16(src + i, dst + i * BLK_STRIDE);
  }

  // ---- Phase-2 tile A ---------------------------------------------------
  {
    float wt0[9] = {aA0.x, aA0.y, aA0.z, aA0.w, aA1.x, aA1.y, aA1.z, aA1.w, aA2.x};
    float wt1[9] = {bA0.x, bA0.y, bA0.z, bA0.w, bA1.x, bA1.y, bA1.z, bA1.w, bA2.x};
    phase2(bufA, lseA, xn, th0A, tw0A, sub, pr, pc0, wt0, wt1,
           hA01.x, hA01.y, hA23.x, hA23.y, hA45.x, hA45.y);
  }

  __syncthreads();   // bar2: drains vmcnt -> tile-B DMA visible

  // ---- Tile-B weights (loads hide under the lse-B exp chain) ------------
  int pixB0 = (th0B + pr) * WW + (tw0B + pc0);
  const float4* apB0 = (const float4*)A + (size_t)pixB0 * 3;
  const float4* apB1 = apB0 + 3;
  float4 aB0 = apB0[0], aB1 = apB0[1], aB2 = apB0[2];
  float4 bB0 = apB1[0], bB1 = apB1[1], bB2 = apB1[2];
  const float2* hpB = (const float2*)(hinv + (size_t)pixB0 * 3);
  float2 hB01 = hpB[0], hB23 = hpB[1], hB45 = hpB[2];

  // ---- lse of tile B from LDS -------------------------------------------
  if (stager) {
    const float4* sp = bufB + wv * WAVE_STRIDE + lane;
    float4 v[12];
#pragma unroll
    for (int i = 0; i < 12; i++) v[i] = sp[i * BLK_STRIDE];
    float4 mv = v[0];
#pragma unroll
    for (int i = 1; i < 12; i++) {
      mv.x = fmaxf(mv.x, v[i].x); mv.y = fmaxf(mv.y, v[i].y);
      mv.z = fmaxf(mv.z, v[i].z); mv.w = fmaxf(mv.w, v[i].w);
    }
    float m = fmaxf(fmaxf(mv.x, mv.y), fmaxf(mv.z, mv.w));
    float sx = 0.f, sy = 0.f, sz = 0.f, sw = 0.f;
#pragma unroll
    for (int i = 0; i < 12; i++) {
      sx += __expf(v[i].x - m); sy += __expf(v[i].y - m);
      sz += __expf(v[i].z - m); sw += __expf(v[i].w - m);
    }
    lseB[t] = m + __logf((sx + sy) + (sz + sw));
  }

  __syncthreads();   // bar3: lse-B ready

  // ---- Phase-2 tile B ---------------------------------------------------
  {
    float wt0[9] = {aB0.x, aB0.y, aB0.z, aB0.w, aB1.x, aB1.y, aB1.z, aB1.w, aB2.x};
    float wt1[9] = {bB0.x, bB0.y, bB0.z, bB0.w, bB1.x, bB1.y, bB1.z, bB1.w, bB2.x};
    phase2(bufB, lseB, xn, th0B, tw0B, sub, pr, pc0, wt0, wt1,
           hB01.x, hB01.y, hB23.x, hB23.y, hB45.x, hB45.y);
  }
}

// ---------------------------------------------------------------------------
// Host launcher.  inputs: v (H,W,48), Dt (H,W,3), dg (H,W,1), hinv (H,W,3)
// ws layout: A[12*HW packed] | xbuf[HW*48]   (~63 MB)
// ping-pong: v -> out -> ws -> out -> ws -> out  (5 steps)
// ---------------------------------------------------------------------------
extern "C" void kernel_launch(void* const* d_in, const int* in_sizes, int n_in,
                              void* d_out, int out_size, void* d_ws, size_t ws_size,
                              hipStream_t stream) {
  const float* v    = (const float*)d_in[0];
  const float* Dt   = (const float*)d_in[1];
  const float* dg   = (const float*)d_in[2];
  const float* hinv = (const float*)d_in[3];
  float* out = (float*)d_out;

  float* A    = (float*)d_ws;
  float* xbuf = A + (size_t)ASTRIDE * HWPIX;

  compute_A_kernel<<<dim3(HWPIX / 256), dim3(256), 0, stream>>>(Dt, dg, A);

  const float* cur = v;
  float* nxt = out;
  for (int s = 0; s < 5; s++) {
    step_fused_kernel<<<dim3(NBLOCKS), dim3(256), 0, stream>>>(cur, A, hinv, nxt);
    if (s == 0) {
      cur = out;
      nxt = xbuf;
    } else {
      float* t = (float*)cur;
      cur = nxt;
      nxt = t;
    }
  }
}

// Round 11
// 216.382 us; speedup vs baseline: 1.0769x; 1.0769x over previous
//
#include <hip/hip_runtime.h>
#include <math.h>

#define HH 512
#define WW 512
#define NCH 48
#define HWPIX (HH * WW)

#define TW 8             // tile width (pixels)
#define TH 8             // tile height
#define HW_HALO 10       // TW + 2
#define HH_HALO 10       // TH + 2
#define NHALO (HW_HALO * HH_HALO)   // 100 halo pixels
#define PSTRIDE 13       // float4 slots per halo pixel (12 + 1 pad)
#define ASTRIDE 12       // floats per pixel in packed A (9 + 3 pad, 16B-aligned)
#define NBLOCKS (HWPIX / 64)        // 4096 tiles of 8x8

// ---------------------------------------------------------------------------
// Kernel 1: packed stencil weights A (border masks + 1/dg + MSQ folded in).
// Pixel-major: A[pix*12 + k] multiplies x[h-1+k/3, w-1+k%3].
// ---------------------------------------------------------------------------
__global__ __launch_bounds__(256) void compute_A_kernel(
    const float* __restrict__ Dt, const float* __restrict__ dg,
    float* __restrict__ A) {
  int pix = blockIdx.x * blockDim.x + threadIdx.x;
  int h = pix >> 9;
  int w = pix & (WW - 1);
  int hm = (h == 0) ? HH - 1 : h - 1;
  int hp = (h == HH - 1) ? 0 : h + 1;
  int wm = (w == 0) ? WW - 1 : w - 1;
  int wp = (w == WW - 1) ? 0 : w + 1;

  float aC, cC, bC, cL, bL, cR, bR, aU, bU, aD, bD;
  float bUL, bUR, bDL, bDR;
  {
    int p;
    p = (h * WW + w) * 3;   aC = Dt[p]; cC = Dt[p + 1]; bC = Dt[p + 2];
    p = (h * WW + wm) * 3;  cL = Dt[p + 1]; bL = Dt[p + 2];
    p = (h * WW + wp) * 3;  cR = Dt[p + 1]; bR = Dt[p + 2];
    p = (hm * WW + w) * 3;  aU = Dt[p]; bU = Dt[p + 2];
    p = (hp * WW + w) * 3;  aD = Dt[p]; bD = Dt[p + 2];
    p = (hm * WW + wm) * 3; bUL = Dt[p + 2];
    p = (hm * WW + wp) * 3; bUR = Dt[p + 2];
    p = (hp * WW + wm) * 3; bDL = Dt[p + 2];
    p = (hp * WW + wp) * 3; bDR = Dt[p + 2];
  }

  float A0 = (fabsf(bDL) - bDL + fabsf(bC) - bC) * 0.25f;
  float A1 = (cL + cC - fabsf(bL) - fabsf(bC)) * 0.5f;
  float A2 = (fabsf(bUL) + bUL + fabsf(bC) + bC) * 0.25f;
  float A3 = (aD + aC - fabsf(bD) - fabsf(bC)) * 0.5f;
  float A4 = -(aD + 2.f * aC + aU) * 0.5f
             - (fabsf(bDL) - bDL + fabsf(bUL) + bUL) * 0.25f
             - (fabsf(bDR) + bDR + fabsf(bUR) - bUR) * 0.25f
             + (fabsf(bD) + fabsf(bU) + fabsf(bR) + fabsf(bL) + 2.f * fabsf(bC)) * 0.5f
             - (cR + 2.f * cC + cL) * 0.5f;
  float A5 = (aU + aC - fabsf(bU) - fabsf(bC)) * 0.5f;
  float A6 = (fabsf(bDR) + bDR + fabsf(bC) + bC) * 0.25f;
  float A7 = (cR + cC - fabsf(bR) - fabsf(bC)) * 0.5f;
  float A8 = (fabsf(bUR) - bUR + fabsf(bC) - bC) * 0.25f;

  bool ru = (h > 0), rd = (h < HH - 1), cl = (w > 0), cr = (w < WW - 1);
  if (!(ru && cl)) A0 = 0.f;
  if (!ru)         A1 = 0.f;
  if (!(ru && cr)) A2 = 0.f;
  if (!cl)         A3 = 0.f;
  if (!cr)         A5 = 0.f;
  if (!(rd && cl)) A6 = 0.f;
  if (!rd)         A7 = 0.f;
  if (!(rd && cr)) A8 = 0.f;

  float g = 1.0f / dg[pix];
  float4* Ao = (float4*)A + (size_t)pix * 3;
  Ao[0] = make_float4(A0 * g, A1 * g, A2 * g, A3 * g);
  Ao[1] = make_float4(A4 * g + 0.1f, A5 * g, A6 * g, A7 * g);
  Ao[2] = make_float4(A8 * g, 0.f, 0.f, 0.f);
}

// ---------------------------------------------------------------------------
// Fused Euler step, 8x8 tile / 128-thread blocks (R11 convoy probe).
// R9/R10 showed FEWER barrier domains per CU is worse; this tests MORE:
//   LDS 21.2 KB -> 7 blocks/CU resident (vs 4), barrier scope 2 waves (vs 4),
//   4096 independent blocks.  Cost: halo over-fetch 1.56x (vs 1.41x).
// Per-block structure is R1/R6-verbatim:
//   Phase 1: threads 0..99 stage one halo pixel (12 float4, periodic wrap)
//     into LDS AND compute its 48-ch lse in-register (load/exp interleave =
//     latency hiding; R5 lesson).  A + hinv prefetched pre-barrier.
//   Phase 2: quad handles a horizontally-adjacent pixel pair; 3x4 LDS patch
//     serves both 3x3 stencils; quad-shuffle channel mean; clipped update.
// XCD-band swizzle: XCD k (= b%8) gets 8 tile rows = pixel rows [64k,64k+64).
// ---------------------------------------------------------------------------
__global__ __launch_bounds__(128, 4) void step_fused_kernel(
    const float* __restrict__ x, const float* __restrict__ A,
    const float* __restrict__ hinv, float* __restrict__ xn) {
  __shared__ float4 tile[NHALO * PSTRIDE];   // 100*13*16 = 20,800 B
  __shared__ float lse_s[NHALO];             // + 400 B

  int b = blockIdx.x;
  int tile_id = (b & 7) * 512 + (b >> 3);    // 4096 tiles, 64 rows x 64 cols
  int th0 = (tile_id >> 6) * TH;
  int tw0 = (tile_id & 63) * TW;

  int t = threadIdx.x;
  int sub = t & 3;                            // interleaved chunk set
  int pair = t >> 2;                          // 0..31
  int pr = pair >> 2;                         // tile row 0..7
  int pc0 = (pair & 3) * 2;                   // even tile col 0..6
  int pix0 = (th0 + pr) * WW + (tw0 + pc0);
  int pix1 = pix0 + 1;

  // ---- Phase 1a: issue halo staging loads (feeds lse + LDS) -------------
  float4 v[12];
  bool stager = (t < NHALO);
  if (stager) {
    int r = t / HW_HALO;
    int c = t - r * HW_HALO;
    int gh = (th0 + r - 1) & (HH - 1);       // periodic wrap
    int gw = (tw0 + c - 1) & (WW - 1);
    const float4* src = (const float4*)x + (size_t)(gh * WW + gw) * 12;
#pragma unroll
    for (int i = 0; i < 12; i++) v[i] = src[i];
  }

  // ---- Phase 1b: prefetch packed stencil weights + hinv (pre-barrier) ----
  const float4* ap0 = (const float4*)A + (size_t)pix0 * 3;
  const float4* ap1 = (const float4*)A + (size_t)pix1 * 3;
  float4 wA0 = ap0[0], wB0 = ap0[1], wC0 = ap0[2];
  float4 wA1 = ap1[0], wB1 = ap1[1], wC1 = ap1[2];
  // 6 consecutive floats for the pair; pix0 is even so base is 8B-aligned
  const float2* hp = (const float2*)(hinv + (size_t)pix0 * 3);
  float2 h01 = hp[0], h23 = hp[1], h45 = hp[2];

  // ---- Phase 1c: lse (parallel chains) + LDS staging writes -------------
  if (stager) {
    float4 mv = v[0];
#pragma unroll
    for (int i = 1; i < 12; i++) {
      mv.x = fmaxf(mv.x, v[i].x); mv.y = fmaxf(mv.y, v[i].y);
      mv.z = fmaxf(mv.z, v[i].z); mv.w = fmaxf(mv.w, v[i].w);
    }
    float m = fmaxf(fmaxf(mv.x, mv.y), fmaxf(mv.z, mv.w));
    float sx = 0.f, sy = 0.f, sz = 0.f, sw = 0.f;
#pragma unroll
    for (int i = 0; i < 12; i++) {
      sx += __expf(v[i].x - m); sy += __expf(v[i].y - m);
      sz += __expf(v[i].z - m); sw += __expf(v[i].w - m);
      tile[t * PSTRIDE + i] = v[i];
    }
    lse_s[t] = m + __logf((sx + sy) + (sz + sw));
  }
  __syncthreads();

  // ---- Phase 2: pixel-pair compute --------------------------------------
  float wt0[9] = {wA0.x, wA0.y, wA0.z, wA0.w, wB0.x, wB0.y, wB0.z, wB0.w, wC0.x};
  float wt1[9] = {wA1.x, wA1.y, wA1.z, wA1.w, wB1.x, wB1.y, wB1.z, wB1.w, wC1.x};
  float ha0 = h01.x, hc0 = h01.y, hb0 = h23.x;
  float ha1 = h23.y, hc1 = h45.x, hb1 = h45.y;

  // lse taps (halo coords: center of px0 = (pr+1, pc0+1))
  int lc0 = (pr + 1) * HW_HALO + (pc0 + 1);
  float l0C = lse_s[lc0];
  float l0R = lse_s[lc0 + 1];                 // = l1C
  float l1R = lse_s[lc0 + 2];
  float l0D = lse_s[lc0 + HW_HALO];
  float l1D = lse_s[lc0 + HW_HALO + 1];
  float dld0 = l0C - l0D, dlr0 = l0C - l0R;
  float dld1 = l0R - l1D, dlr1 = l0R - l1R;

  // LDS float4-offsets of the 3x4 patch (rows pr..pr+2, cols pc0..pc0+3)
  int poff[3][4];
#pragma unroll
  for (int dr = 0; dr < 3; dr++)
#pragma unroll
    for (int dc = 0; dc < 4; dc++)
      poff[dr][dc] = ((pr + dr) * HW_HALO + pc0 + dc) * PSTRIDE;

  float4 vals0[3], vals1[3];
  float sum0 = 0.f, sum1 = 0.f;
#pragma unroll
  for (int j = 0; j < 3; j++) {
    int ch = j * 4 + sub;
    float4 q[3][4];
#pragma unroll
    for (int dr = 0; dr < 3; dr++)
#pragma unroll
      for (int dc = 0; dc < 4; dc++) q[dr][dc] = tile[poff[dr][dc] + ch];

    float4 val0, val1;
#define COMP(f)                                                                \
    {                                                                          \
      float s0_ = wt0[0] * q[0][0].f + wt0[1] * q[0][1].f + wt0[2] * q[0][2].f \
                + wt0[3] * q[1][0].f + wt0[4] * q[1][1].f + wt0[5] * q[1][2].f \
                + wt0[6] * q[2][0].f + wt0[7] * q[2][1].f + wt0[8] * q[2][2].f;\
      float v00 = q[2][1].f - q[1][1].f + dld0;                                \
      float v10 = q[1][2].f - q[1][1].f + dlr0;                                \
      float vv0 = s0_ + 0.5f * (ha0 * v00 * v00 + hc0 * v10 * v10) +           \
                  hb0 * (v00 * v10);                                           \
      val0.f = vv0; sum0 += vv0;                                               \
      float s1_ = wt1[0] * q[0][1].f + wt1[1] * q[0][2].f + wt1[2] * q[0][3].f \
                + wt1[3] * q[1][1].f + wt1[4] * q[1][2].f + wt1[5] * q[1][3].f \
                + wt1[6] * q[2][1].f + wt1[7] * q[2][2].f + wt1[8] * q[2][3].f;\
      float v01 = q[2][2].f - q[1][2].f + dld1;                                \
      float v11 = q[1][3].f - q[1][2].f + dlr1;                                \
      float vv1 = s1_ + 0.5f * (ha1 * v01 * v01 + hc1 * v11 * v11) +           \
                  hb1 * (v01 * v11);                                           \
      val1.f = vv1; sum1 += vv1;                                               \
    }
    COMP(x) COMP(y) COMP(z) COMP(w)
#undef COMP
    vals0[j] = val0;
    vals1[j] = val1;
  }

  // channel mean across the 4-thread quad (48 channels per pixel)
  sum0 += __shfl_xor(sum0, 1); sum0 += __shfl_xor(sum0, 2);
  sum1 += __shfl_xor(sum1, 1); sum1 += __shfl_xor(sum1, 2);
  float mean0 = sum0 * (1.0f / 48.0f);
  float mean1 = sum1 * (1.0f / 48.0f);

  // centers re-read from LDS (saves 24 VGPRs vs holding them live)
  int cen0 = lc0 * PSTRIDE;                   // px0 center halo offset
  float4* op0 = (float4*)(xn + (size_t)pix0 * NCH);
  float4* op1 = op0 + 12;
#pragma unroll
  for (int j = 0; j < 3; j++) {
    int ch = j * 4 + sub;
    float4 c0 = tile[cen0 + ch];
    float4 c1 = tile[cen0 + PSTRIDE + ch];
    float4 r0, r1;
    r0.x = c0.x + 0.2f * fminf(fmaxf(vals0[j].x - mean0, -1e8f), 1e8f);
    r0.y = c0.y + 0.2f * fminf(fmaxf(vals0[j].y - mean0, -1e8f), 1e8f);
    r0.z = c0.z + 0.2f * fminf(fmaxf(vals0[j].z - mean0, -1e8f), 1e8f);
    r0.w = c0.w + 0.2f * fminf(fmaxf(vals0[j].w - mean0, -1e8f), 1e8f);
    r1.x = c1.x + 0.2f * fminf(fmaxf(vals1[j].x - mean1, -1e8f), 1e8f);
    r1.y = c1.y + 0.2f * fminf(fmaxf(vals1[j].y - mean1, -1e8f), 1e8f);
    r1.z = c1.z + 0.2f * fminf(fmaxf(vals1[j].z - mean1, -1e8f), 1e8f);
    r1.w = c1.w + 0.2f * fminf(fmaxf(vals1[j].w - mean1, -1e8f), 1e8f);
    op0[ch] = r0;
    op1[ch] = r1;
  }
}

// ---------------------------------------------------------------------------
// Host launcher.  inputs: v (H,W,48), Dt (H,W,3), dg (H,W,1), hinv (H,W,3)
// ws layout: A[12*HW packed] | xbuf[HW*48]   (~63 MB)
// ping-pong: v -> out -> ws -> out -> ws -> out  (5 steps)
// ---------------------------------------------------------------------------
extern "C" void kernel_launch(void* const* d_in, const int* in_sizes, int n_in,
                              void* d_out, int out_size, void* d_ws, size_t ws_size,
                              hipStream_t stream) {
  const float* v    = (const float*)d_in[0];
  const float* Dt   = (const float*)d_in[1];
  const float* dg   = (const float*)d_in[2];
  const float* hinv = (const float*)d_in[3];
  float* out = (float*)d_out;

  float* A    = (float*)d_ws;
  float* xbuf = A + (size_t)ASTRIDE * HWPIX;

  compute_A_kernel<<<dim3(HWPIX / 256), dim3(256), 0, stream>>>(Dt, dg, A);

  const float* cur = v;
  float* nxt = out;
  for (int s = 0; s < 5; s++) {
    step_fused_kernel<<<dim3(NBLOCKS), dim3(128), 0, stream>>>(cur, A, hinv, nxt);
    if (s == 0) {
      cur = out;
      nxt = xbuf;
    } else {
      float* t = (float*)cur;
      cur = nxt;
      nxt = t;
    }
  }
}